// Round 1
// baseline (7927.894 us; speedup 1.0000x reference)
//
#include <hip/hip_runtime.h>
#include <math.h>

#define BB 512
#define TT 720
#define DD 774
#define PP 128
#define HH 128
#define GG 512      // 4*H
#define DP2 776     // D+2
#define TAB 721

__device__ __forceinline__ float gelu_f(float v){
    return 0.5f*v*(1.0f + erff(v*0.70710678118654752f));
}
__device__ __forceinline__ float sig_f(float v){
    return 1.0f/(1.0f + __expf(-v));
}

// ---------------- K0: zero states ----------------
__global__ void k_zero(float* __restrict__ p, int n){
    int i = blockIdx.x*256 + threadIdx.x;
    if (i < n) p[i] = 0.f;
}

// ---------------- K1: has flags (wave per row) ----------------
__global__ __launch_bounds__(256) void k_has(const float* __restrict__ x, float* __restrict__ has){
    int wid  = blockIdx.x*4 + (threadIdx.x >> 6);
    int lane = threadIdx.x & 63;
    const float2* row = reinterpret_cast<const float2*>(x + (size_t)wid*DD); // 774 floats = 387 float2
    float s = 0.f;
    #pragma unroll
    for (int i=0;i<6;i++){ float2 v = row[lane + i*64]; s += fabsf(v.x)+fabsf(v.y); }
    if (lane < 3){ float2 v = row[384 + lane]; s += fabsf(v.x)+fabsf(v.y); }
    #pragma unroll
    for (int off=32; off; off>>=1) s += __shfl_down(s, off, 64);
    if (lane == 0) has[wid] = (s > 1e-6f) ? 1.0f : 0.0f;
}

// ---------------- K2: recency + per-(b,chunk) dense counts ----------------
__global__ void k_rec(const float* __restrict__ has, int* __restrict__ recIdx,
                      int* __restrict__ cnt_bc, int Tc, int NC){
    int b = blockIdx.x*64 + threadIdx.x;
    if (b >= BB) return;
    const float* hp = has + (size_t)b*TT;
    int* rp = recIdx + (size_t)b*TT;
    int last = -1, cl = 0, c = 0;
    for (int t=0;t<TT;t++){
        if (t == (c+1)*Tc){ cnt_bc[b*NC + c] = cl; cl = 0; c++; }
        if (hp[t] > 0.5f){ last = t; cl++; }
        rp[t] = t - last;   // dense -> 0 ; sparse -> k in [1,720]
    }
    cnt_bc[b*NC + c] = cl;
}

// ---------------- K2b: exclusive prefix over b per chunk ----------------
__global__ __launch_bounds__(512) void k_scan(const int* __restrict__ cnt_bc, int* __restrict__ base_bc,
                                              int* __restrict__ cntTotal, int NC){
    int c = blockIdx.x;
    int b = threadIdx.x;
    int v = cnt_bc[b*NC + c];
    int lane = b & 63, w = b >> 6;
    int xv = v;
    #pragma unroll
    for (int off=1; off<64; off<<=1){
        int y = __shfl_up(xv, off, 64);
        if (lane >= off) xv += y;
    }
    __shared__ int wsums[8];
    if (lane == 63) wsums[w] = xv;
    __syncthreads();
    if (b == 0){
        int run = 0;
        #pragma unroll
        for (int i=0;i<8;i++){ int tv = wsums[i]; wsums[i] = run; run += tv; }
        cntTotal[c] = run;
    }
    __syncthreads();
    base_bc[b*NC + c] = wsums[w] + xv - v;  // exclusive prefix
}

// ---------------- K2c: dense-row lists + positions ----------------
__global__ void k_pos(const float* __restrict__ has, const int* __restrict__ base_bc,
                      int* __restrict__ posIdx, int* __restrict__ list, int Tc, int NC){
    int b = blockIdx.x*64 + threadIdx.x;
    if (b >= BB) return;
    const float* hp = has + (size_t)b*TT;
    int c = 0;
    int pos = base_bc[b*NC + 0];
    for (int t=0;t<TT;t++){
        if (t == (c+1)*Tc){ c++; pos = base_bc[b*NC + c]; }
        int r = b*TT + t;
        if (hp[t] > 0.5f){
            posIdx[r] = pos;
            list[(size_t)c*((size_t)BB*Tc) + pos] = r;
            pos++;
        } else {
            posIdx[r] = -1;
        }
    }
}

// ---------------- K_tab1: h0 rows for sparse rows, per rec index ----------------
__global__ __launch_bounds__(128) void k_tab1(const float* __restrict__ wp, const float* __restrict__ bp,
        const float* __restrict__ lng, const float* __restrict__ lnb, float* __restrict__ tab1){
    int k = blockIdx.x, j = threadIdx.x;
    float rec = (float)k * (1.0f/720.0f);
    float v = gelu_f(rec * wp[775*PP + j] + bp[j]);
    int lane = j & 63, w = j >> 6;
    __shared__ float red[2];
    float s = v;
    #pragma unroll
    for (int off=32; off; off>>=1) s += __shfl_xor(s, off, 64);
    if (lane == 0) red[w] = s;
    __syncthreads();
    float mu = (red[0] + red[1]) * (1.0f/128.0f);
    __syncthreads();
    float d = v - mu, s2 = d*d;
    #pragma unroll
    for (int off=32; off; off>>=1) s2 += __shfl_xor(s2, off, 64);
    if (lane == 0) red[w] = s2;
    __syncthreads();
    float var = (red[0] + red[1]) * (1.0f/128.0f);
    tab1[k*PP + j] = d * rsqrtf(var + 1e-5f) * lng[j] + lnb[j];
}

// ---------------- K_tab2: pre0 rows for sparse rows ----------------
__global__ __launch_bounds__(512) void k_tab2(const float* __restrict__ tab1, const float* __restrict__ wih,
        const float* __restrict__ bih, const float* __restrict__ bhh, float* __restrict__ tab2){
    int k = blockIdx.x, j = threadIdx.x;
    __shared__ float hrow[PP];
    if (j < PP) hrow[j] = tab1[k*PP + j];
    __syncthreads();
    float acc = bih[j] + bhh[j];
    #pragma unroll
    for (int kk=0; kk<PP; kk++) acc += hrow[kk]*wih[kk*GG + j];
    tab2[(size_t)k*GG + j] = acc;
}

// ---------------- K3: projection + GELU + LN for dense rows of one chunk ----------------
__global__ __launch_bounds__(256) void k_proj(const float* __restrict__ x,
        const float* __restrict__ wp, const float* __restrict__ bp,
        const float* __restrict__ lng, const float* __restrict__ lnb,
        const int* __restrict__ listc, const int* __restrict__ cntPtr,
        float* __restrict__ h0c){
    int nc = cntPtr[0];
    int base = blockIdx.x*16;
    if (base >= nc) return;
    int nrows = min(16, nc - base);
    __shared__ float xs[16][DP2];
    __shared__ float hls[16][PP];
    __shared__ float mvs[16][2];
    const int tid = threadIdx.x;
    for (int rr=0; rr<16; rr++){
        if (rr < nrows){
            int row = listc[base + rr];
            const float* xr = x + (size_t)row*DD;
            for (int d = tid; d < DD; d += 256) xs[rr][d] = xr[d];
            if (tid == 0){ xs[rr][774] = 1.0f; xs[rr][775] = 0.0f; } // has=1, rec=0 for dense rows
        }
    }
    __syncthreads();
    int col = tid & 127, rg = tid >> 7;
    float acc[8];
    #pragma unroll
    for (int r=0;r<8;r++) acc[r] = bp[col];
    const float* wcol = wp + col;
    for (int d=0; d<DP2; d+=4){
        float w0 = wcol[(d+0)*PP], w1 = wcol[(d+1)*PP], w2 = wcol[(d+2)*PP], w3 = wcol[(d+3)*PP];
        #pragma unroll
        for (int r=0;r<8;r++){
            float4 xv = *reinterpret_cast<const float4*>(&xs[rg*8 + r][d]);
            acc[r] = fmaf(xv.x, w0, acc[r]);
            acc[r] = fmaf(xv.y, w1, acc[r]);
            acc[r] = fmaf(xv.z, w2, acc[r]);
            acc[r] = fmaf(xv.w, w3, acc[r]);
        }
    }
    #pragma unroll
    for (int r=0;r<8;r++){ acc[r] = gelu_f(acc[r]); hls[rg*8 + r][col] = acc[r]; }
    __syncthreads();
    int w = tid >> 6, lane = tid & 63;
    for (int rr = w*4; rr < w*4 + 4; rr++){
        float s = hls[rr][lane] + hls[rr][lane + 64];
        #pragma unroll
        for (int off=32; off; off>>=1) s += __shfl_xor(s, off, 64);
        float mu = s * (1.0f/128.0f);
        float d0 = hls[rr][lane]-mu, d1 = hls[rr][lane+64]-mu;
        float s2 = d0*d0 + d1*d1;
        #pragma unroll
        for (int off=32; off; off>>=1) s2 += __shfl_xor(s2, off, 64);
        if (lane == 0){ mvs[rr][0] = mu; mvs[rr][1] = rsqrtf(s2*(1.0f/128.0f) + 1e-5f); }
    }
    __syncthreads();
    float g = lng[col], bb = lnb[col];
    #pragma unroll
    for (int r=0;r<8;r++){
        int rr = rg*8 + r;
        if (base + rr < nc){
            float o = (acc[r] - mvs[rr][0]) * mvs[rr][1] * g + bb;
            h0c[(size_t)(base+rr)*PP + col] = o;
        }
    }
}

// ---------------- K4: [rows x 128] @ [128 x 512] + bih + bhh ----------------
__global__ __launch_bounds__(512) void k_pre(const float* __restrict__ inM,
        const float* __restrict__ wih, const float* __restrict__ bih, const float* __restrict__ bhh,
        const int* __restrict__ cntPtr, int fixedCount, float* __restrict__ outPre){
    int nc = cntPtr ? cntPtr[0] : fixedCount;
    int base = blockIdx.x*32;
    if (base >= nc) return;
    __shared__ float hs[32][PP];
    int tid = threadIdx.x;
    for (int i = tid; i < 32*PP; i += 512){
        int rr = i >> 7;
        if (base + rr < nc) hs[rr][i & 127] = inM[(size_t)(base+rr)*PP + (i & 127)];
    }
    __syncthreads();
    float bias = bih[tid] + bhh[tid];
    float acc[32];
    #pragma unroll
    for (int r=0;r<32;r++) acc[r] = bias;
    const float* wc = wih + tid;
    for (int k=0;k<PP;k+=4){
        float w0 = wc[(k+0)*GG], w1 = wc[(k+1)*GG], w2 = wc[(k+2)*GG], w3 = wc[(k+3)*GG];
        #pragma unroll
        for (int r=0;r<32;r++){
            float4 hv = *reinterpret_cast<const float4*>(&hs[r][k]);
            acc[r] = fmaf(hv.x, w0, acc[r]);
            acc[r] = fmaf(hv.y, w1, acc[r]);
            acc[r] = fmaf(hv.z, w2, acc[r]);
            acc[r] = fmaf(hv.w, w3, acc[r]);
        }
    }
    #pragma unroll
    for (int r=0;r<32;r++)
        if (base + r < nc) outPre[(size_t)(base+r)*GG + tid] = acc[r];
}

// ---------------- K5: LSTM recurrence, one batch row per block ----------------
__global__ __launch_bounds__(512, 2) void k_lstm(
    const float* __restrict__ whh, const float* __restrict__ pre,
    const float* __restrict__ pretab, const int* __restrict__ posIdx,
    const int* __restrict__ recIdx, float* __restrict__ hState, float* __restrict__ cState,
    float* __restrict__ hsOut, int t0, int Tc, int layer)
{
    int b = blockIdx.x;
    int j = threadIdx.x;
    float w[128];
    #pragma unroll
    for (int k=0;k<128;k++) w[k] = whh[k*GG + j];   // column j of Whh in VGPRs
    __shared__ float hbuf[HH];
    __shared__ float hprev[HH];
    __shared__ float gbuf[GG];
    if (j < HH) hbuf[j] = hState[b*HH + j];
    float c_ = (j < HH) ? cState[b*HH + j] : 0.f;
    __syncthreads();
    for (int t = t0; t < t0 + Tc; t++){
        // early-issue previous step's hs store (hides store-drain at barrier under FMA)
        if (hsOut && t > t0 && j >= 128 && j < 256)
            hsOut[((size_t)(t-1-t0)*BB + b)*HH + (j-128)] = hprev[j-128];
        float p0;
        if (layer == 0){
            int pos = posIdx[(size_t)b*TT + t];
            const float* src = (pos >= 0) ? (pre + (size_t)pos*GG)
                                          : (pretab + (size_t)recIdx[(size_t)b*TT + t]*GG);
            p0 = src[j];
        } else {
            p0 = pre[((size_t)(t-t0)*BB + b)*GG + j];
        }
        float a0=0.f, a1=0.f, a2=0.f, a3=0.f;
        #pragma unroll
        for (int k=0;k<128;k+=16){
            float4 h0v = *reinterpret_cast<const float4*>(&hbuf[k]);
            float4 h1v = *reinterpret_cast<const float4*>(&hbuf[k+4]);
            float4 h2v = *reinterpret_cast<const float4*>(&hbuf[k+8]);
            float4 h3v = *reinterpret_cast<const float4*>(&hbuf[k+12]);
            a0 = fmaf(h0v.x, w[k+0],  a0); a0 = fmaf(h0v.y, w[k+1],  a0);
            a0 = fmaf(h0v.z, w[k+2],  a0); a0 = fmaf(h0v.w, w[k+3],  a0);
            a1 = fmaf(h1v.x, w[k+4],  a1); a1 = fmaf(h1v.y, w[k+5],  a1);
            a1 = fmaf(h1v.z, w[k+6],  a1); a1 = fmaf(h1v.w, w[k+7],  a1);
            a2 = fmaf(h2v.x, w[k+8],  a2); a2 = fmaf(h2v.y, w[k+9],  a2);
            a2 = fmaf(h2v.z, w[k+10], a2); a2 = fmaf(h2v.w, w[k+11], a2);
            a3 = fmaf(h3v.x, w[k+12], a3); a3 = fmaf(h3v.y, w[k+13], a3);
            a3 = fmaf(h3v.z, w[k+14], a3); a3 = fmaf(h3v.w, w[k+15], a3);
        }
        gbuf[j] = p0 + ((a0+a1)+(a2+a3));
        __syncthreads();
        if (j < HH){
            float gi = gbuf[j], gf = gbuf[HH+j], gg = gbuf[2*HH+j], go = gbuf[3*HH+j];
            c_ = sig_f(gf)*c_ + sig_f(gi)*tanhf(gg);
            float hn = sig_f(go)*tanhf(c_);
            hbuf[j] = hn;
            hprev[j] = hn;
        }
        __syncthreads();
    }
    if (hsOut && j >= 128 && j < 256)
        hsOut[((size_t)(Tc-1)*BB + b)*HH + (j-128)] = hprev[j-128];
    if (j < HH){ hState[b*HH + j] = hbuf[j]; cState[b*HH + j] = c_; }
}

// ---------------- K6: heads ----------------
__global__ __launch_bounds__(128) void k_head(const float* __restrict__ hS,
        const float* __restrict__ we1, const float* __restrict__ be1,
        const float* __restrict__ we2, const float* __restrict__ be2,
        const float* __restrict__ wr,  const float* __restrict__ br,
        const float* __restrict__ wo,  const float* __restrict__ bo,
        const float* __restrict__ wsv, float* __restrict__ out){
    int b = blockIdx.x, j = threadIdx.x;
    __shared__ float lh[128], e1[128], hr[64];
    lh[j] = hS[b*128 + j];
    __syncthreads();
    float acc = be1[j];
    #pragma unroll
    for (int k=0;k<128;k++) acc += lh[k]*we1[k*128 + j];
    e1[j] = gelu_f(acc);
    if (j < 64){
        float a2 = br[j];
        #pragma unroll
        for (int k=0;k<128;k++) a2 += lh[k]*wr[k*64 + j];
        hr[j] = gelu_f(a2);
    }
    __syncthreads();
    if (j < 64){
        float a3 = be2[j];
        #pragma unroll
        for (int k=0;k<128;k++) a3 += e1[k]*we2[k*64 + j];
        out[BB + b*64 + j] = tanhf(a3);
        float p = hr[j]*wo[j] + lh[j]*wsv[j] + lh[j+64]*wsv[j+64];
        #pragma unroll
        for (int off=32; off; off>>=1) p += __shfl_down(p, off, 64);
        if (j == 0) out[b] = p + bo[0];
    }
}

extern "C" void kernel_launch(void* const* d_in, const int* in_sizes, int n_in,
                              void* d_out, int out_size, void* d_ws, size_t ws_size,
                              hipStream_t stream) {
    const float* x     = (const float*)d_in[0];
    const float* wproj = (const float*)d_in[1];
    const float* bproj = (const float*)d_in[2];
    const float* lng   = (const float*)d_in[3];
    const float* lnb   = (const float*)d_in[4];
    const float* wih0  = (const float*)d_in[5];
    const float* whh0  = (const float*)d_in[6];
    const float* bih0  = (const float*)d_in[7];
    const float* bhh0  = (const float*)d_in[8];
    const float* wih1  = (const float*)d_in[9];
    const float* whh1  = (const float*)d_in[10];
    const float* bih1  = (const float*)d_in[11];
    const float* bhh1  = (const float*)d_in[12];
    const float* we1   = (const float*)d_in[13];
    const float* be1   = (const float*)d_in[14];
    const float* we2   = (const float*)d_in[15];
    const float* be2   = (const float*)d_in[16];
    const float* wr    = (const float*)d_in[17];
    const float* br    = (const float*)d_in[18];
    const float* wo    = (const float*)d_in[19];
    const float* bo    = (const float*)d_in[20];
    const float* wsv   = (const float*)d_in[21];
    float* out = (float*)d_out;

    const size_t BT = (size_t)BB*TT;
    static const int cands[12] = {90,60,45,30,20,15,10,6,5,3,2,1};
    size_t offs[12];
    auto plan = [&](int tc, size_t* o)->size_t{
        size_t NCc = (size_t)(TT / tc);
        size_t cur = 0;
        auto take = [&](size_t bytes){ size_t r = cur; cur = (cur + bytes + 255) & ~(size_t)255; return r; };
        o[0]  = take(BT*4);                 // has
        o[1]  = take(BT*4);                 // recIdx
        o[2]  = take(BT*4);                 // posIdx
        o[3]  = take(BT*4);                 // list
        o[4]  = take((size_t)BB*NCc*4);     // cnt_bc
        o[5]  = take((size_t)BB*NCc*4);     // base_bc
        o[6]  = take(NCc*4);                // cntTotal
        o[7]  = take((size_t)TAB*PP*4);     // tab1
        o[8]  = take((size_t)TAB*GG*4);     // tab2
        o[9]  = take((size_t)4*BB*HH*4);    // states h0,c0,h1,c1
        o[10] = take((size_t)BB*tc*PP*4);   // h0buf / hs0buf (aliased)
        o[11] = take((size_t)BB*tc*GG*4);   // prebuf (pre0 then pre1, aliased)
        return cur;
    };
    int Tc = 1;
    for (int ci=0; ci<12; ci++){
        if (plan(cands[ci], offs) <= ws_size){ Tc = cands[ci]; break; }
    }
    plan(Tc, offs);
    char* wsb = (char*)d_ws;
    float* f_has    = (float*)(wsb + offs[0]);
    int*   i_rec    = (int*)  (wsb + offs[1]);
    int*   i_pos    = (int*)  (wsb + offs[2]);
    int*   i_list   = (int*)  (wsb + offs[3]);
    int*   i_cntbc  = (int*)  (wsb + offs[4]);
    int*   i_basebc = (int*)  (wsb + offs[5]);
    int*   i_cnt    = (int*)  (wsb + offs[6]);
    float* f_tab1   = (float*)(wsb + offs[7]);
    float* f_tab2   = (float*)(wsb + offs[8]);
    float* f_st     = (float*)(wsb + offs[9]);
    float* f_h0     = (float*)(wsb + offs[10]);
    float* f_pre    = (float*)(wsb + offs[11]);
    const int NC = TT / Tc;

    float* st_h0 = f_st;
    float* st_c0 = f_st + (size_t)BB*HH;
    float* st_h1 = f_st + (size_t)2*BB*HH;
    float* st_c1 = f_st + (size_t)3*BB*HH;

    { int n = 4*BB*HH; k_zero<<<(n+255)/256, 256, 0, stream>>>(f_st, n); }
    k_has <<<(int)(BT/4), 256, 0, stream>>>(x, f_has);
    k_rec <<<(BB+63)/64, 64, 0, stream>>>(f_has, i_rec, i_cntbc, Tc, NC);
    k_scan<<<NC, 512, 0, stream>>>(i_cntbc, i_basebc, i_cnt, NC);
    k_pos <<<(BB+63)/64, 64, 0, stream>>>(f_has, i_basebc, i_pos, i_list, Tc, NC);
    k_tab1<<<TAB, 128, 0, stream>>>(wproj, bproj, lng, lnb, f_tab1);
    k_tab2<<<TAB, 512, 0, stream>>>(f_tab1, wih0, bih0, bhh0, f_tab2);

    const int rowsPerChunk = BB*Tc;
    for (int c=0; c<NC; c++){
        const int* listc = i_list + (size_t)c*rowsPerChunk;
        k_proj<<<(rowsPerChunk+15)/16, 256, 0, stream>>>(x, wproj, bproj, lng, lnb,
                listc, i_cnt + c, f_h0);
        k_pre <<<(rowsPerChunk+31)/32, 512, 0, stream>>>(f_h0, wih0, bih0, bhh0,
                i_cnt + c, 0, f_pre);
        k_lstm<<<BB, 512, 0, stream>>>(whh0, f_pre, f_tab2, i_pos, i_rec,
                st_h0, st_c0, f_h0, c*Tc, Tc, 0);
        k_pre <<<(rowsPerChunk+31)/32, 512, 0, stream>>>(f_h0, wih1, bih1, bhh1,
                nullptr, rowsPerChunk, f_pre);
        k_lstm<<<BB, 512, 0, stream>>>(whh1, f_pre, nullptr, nullptr, nullptr,
                st_h1, st_c1, nullptr, c*Tc, Tc, 1);
    }
    k_head<<<BB, 128, 0, stream>>>(st_h1, we1, be1, we2, be2, wr, br, wo, bo, wsv, out);
}

// Round 2
// 7888.421 us; speedup vs baseline: 1.0050x; 1.0050x over previous
//
#include <hip/hip_runtime.h>
#include <math.h>

#define BB 512
#define TT 720
#define DD 774
#define PP 128
#define HH 128
#define GG 512      // 4*H
#define DP2 776     // D+2
#define TAB 721

__device__ __forceinline__ float gelu_f(float v){
    return 0.5f*v*(1.0f + erff(v*0.70710678118654752f));
}
__device__ __forceinline__ float sig_f(float v){
    return 1.0f/(1.0f + __expf(-v));
}

// ---------------- K0: zero states ----------------
__global__ void k_zero(float* __restrict__ p, int n){
    int i = blockIdx.x*256 + threadIdx.x;
    if (i < n) p[i] = 0.f;
}

// ---------------- K1: has flags (wave per row) ----------------
__global__ __launch_bounds__(256) void k_has(const float* __restrict__ x, float* __restrict__ has){
    int wid  = blockIdx.x*4 + (threadIdx.x >> 6);
    int lane = threadIdx.x & 63;
    const float2* row = reinterpret_cast<const float2*>(x + (size_t)wid*DD); // 774 floats = 387 float2
    float s = 0.f;
    #pragma unroll
    for (int i=0;i<6;i++){ float2 v = row[lane + i*64]; s += fabsf(v.x)+fabsf(v.y); }
    if (lane < 3){ float2 v = row[384 + lane]; s += fabsf(v.x)+fabsf(v.y); }
    #pragma unroll
    for (int off=32; off; off>>=1) s += __shfl_down(s, off, 64);
    if (lane == 0) has[wid] = (s > 1e-6f) ? 1.0f : 0.0f;
}

// ---------------- K2: recency + per-(b,chunk) dense counts ----------------
__global__ void k_rec(const float* __restrict__ has, int* __restrict__ recIdx,
                      int* __restrict__ cnt_bc, int Tc, int NC){
    int b = blockIdx.x*64 + threadIdx.x;
    if (b >= BB) return;
    const float* hp = has + (size_t)b*TT;
    int* rp = recIdx + (size_t)b*TT;
    int last = -1, cl = 0, c = 0;
    for (int t=0;t<TT;t++){
        if (t == (c+1)*Tc){ cnt_bc[b*NC + c] = cl; cl = 0; c++; }
        if (hp[t] > 0.5f){ last = t; cl++; }
        rp[t] = t - last;   // dense -> 0 ; sparse -> k in [1,720]
    }
    cnt_bc[b*NC + c] = cl;
}

// ---------------- K2b: exclusive prefix over b per chunk ----------------
__global__ __launch_bounds__(512) void k_scan(const int* __restrict__ cnt_bc, int* __restrict__ base_bc,
                                              int* __restrict__ cntTotal, int NC){
    int c = blockIdx.x;
    int b = threadIdx.x;
    int v = cnt_bc[b*NC + c];
    int lane = b & 63, w = b >> 6;
    int xv = v;
    #pragma unroll
    for (int off=1; off<64; off<<=1){
        int y = __shfl_up(xv, off, 64);
        if (lane >= off) xv += y;
    }
    __shared__ int wsums[8];
    if (lane == 63) wsums[w] = xv;
    __syncthreads();
    if (b == 0){
        int run = 0;
        #pragma unroll
        for (int i=0;i<8;i++){ int tv = wsums[i]; wsums[i] = run; run += tv; }
        cntTotal[c] = run;
    }
    __syncthreads();
    base_bc[b*NC + c] = wsums[w] + xv - v;  // exclusive prefix
}

// ---------------- K2c: dense-row lists + positions ----------------
__global__ void k_pos(const float* __restrict__ has, const int* __restrict__ base_bc,
                      int* __restrict__ posIdx, int* __restrict__ list, int Tc, int NC){
    int b = blockIdx.x*64 + threadIdx.x;
    if (b >= BB) return;
    const float* hp = has + (size_t)b*TT;
    int c = 0;
    int pos = base_bc[b*NC + 0];
    for (int t=0;t<TT;t++){
        if (t == (c+1)*Tc){ c++; pos = base_bc[b*NC + c]; }
        int r = b*TT + t;
        if (hp[t] > 0.5f){
            posIdx[r] = pos;
            list[(size_t)c*((size_t)BB*Tc) + pos] = r;
            pos++;
        } else {
            posIdx[r] = -1;
        }
    }
}

// ---------------- K_tab1: h0 rows for sparse rows, per rec index ----------------
__global__ __launch_bounds__(128) void k_tab1(const float* __restrict__ wp, const float* __restrict__ bp,
        const float* __restrict__ lng, const float* __restrict__ lnb, float* __restrict__ tab1){
    int k = blockIdx.x, j = threadIdx.x;
    float rec = (float)k * (1.0f/720.0f);
    float v = gelu_f(rec * wp[775*PP + j] + bp[j]);
    int lane = j & 63, w = j >> 6;
    __shared__ float red[2];
    float s = v;
    #pragma unroll
    for (int off=32; off; off>>=1) s += __shfl_xor(s, off, 64);
    if (lane == 0) red[w] = s;
    __syncthreads();
    float mu = (red[0] + red[1]) * (1.0f/128.0f);
    __syncthreads();
    float d = v - mu, s2 = d*d;
    #pragma unroll
    for (int off=32; off; off>>=1) s2 += __shfl_xor(s2, off, 64);
    if (lane == 0) red[w] = s2;
    __syncthreads();
    float var = (red[0] + red[1]) * (1.0f/128.0f);
    tab1[k*PP + j] = d * rsqrtf(var + 1e-5f) * lng[j] + lnb[j];
}

// ---------------- K_tab2: pre0 rows for sparse rows ----------------
__global__ __launch_bounds__(512) void k_tab2(const float* __restrict__ tab1, const float* __restrict__ wih,
        const float* __restrict__ bih, const float* __restrict__ bhh, float* __restrict__ tab2){
    int k = blockIdx.x, j = threadIdx.x;
    __shared__ float hrow[PP];
    if (j < PP) hrow[j] = tab1[k*PP + j];
    __syncthreads();
    float acc = bih[j] + bhh[j];
    #pragma unroll
    for (int kk=0; kk<PP; kk++) acc += hrow[kk]*wih[kk*GG + j];
    tab2[(size_t)k*GG + j] = acc;
}

// ---------------- K3: projection + GELU + LN for dense rows of one chunk ----------------
__global__ __launch_bounds__(256) void k_proj(const float* __restrict__ x,
        const float* __restrict__ wp, const float* __restrict__ bp,
        const float* __restrict__ lng, const float* __restrict__ lnb,
        const int* __restrict__ listc, const int* __restrict__ cntPtr,
        float* __restrict__ h0c){
    int nc = cntPtr[0];
    int base = blockIdx.x*16;
    if (base >= nc) return;
    int nrows = min(16, nc - base);
    __shared__ float xs[16][DP2];
    __shared__ float hls[16][PP];
    __shared__ float mvs[16][2];
    const int tid = threadIdx.x;
    for (int rr=0; rr<16; rr++){
        if (rr < nrows){
            int row = listc[base + rr];
            const float* xr = x + (size_t)row*DD;
            for (int d = tid; d < DD; d += 256) xs[rr][d] = xr[d];
            if (tid == 0){ xs[rr][774] = 1.0f; xs[rr][775] = 0.0f; } // has=1, rec=0 for dense rows
        }
    }
    __syncthreads();
    int col = tid & 127, rg = tid >> 7;
    float acc[8];
    #pragma unroll
    for (int r=0;r<8;r++) acc[r] = bp[col];
    const float* wcol = wp + col;
    for (int d=0; d<DP2; d+=4){
        float w0 = wcol[(d+0)*PP], w1 = wcol[(d+1)*PP], w2 = wcol[(d+2)*PP], w3 = wcol[(d+3)*PP];
        #pragma unroll
        for (int r=0;r<8;r++){
            float4 xv = *reinterpret_cast<const float4*>(&xs[rg*8 + r][d]);
            acc[r] = fmaf(xv.x, w0, acc[r]);
            acc[r] = fmaf(xv.y, w1, acc[r]);
            acc[r] = fmaf(xv.z, w2, acc[r]);
            acc[r] = fmaf(xv.w, w3, acc[r]);
        }
    }
    #pragma unroll
    for (int r=0;r<8;r++){ acc[r] = gelu_f(acc[r]); hls[rg*8 + r][col] = acc[r]; }
    __syncthreads();
    int w = tid >> 6, lane = tid & 63;
    for (int rr = w*4; rr < w*4 + 4; rr++){
        float s = hls[rr][lane] + hls[rr][lane + 64];
        #pragma unroll
        for (int off=32; off; off>>=1) s += __shfl_xor(s, off, 64);
        float mu = s * (1.0f/128.0f);
        float d0 = hls[rr][lane]-mu, d1 = hls[rr][lane+64]-mu;
        float s2 = d0*d0 + d1*d1;
        #pragma unroll
        for (int off=32; off; off>>=1) s2 += __shfl_xor(s2, off, 64);
        if (lane == 0){ mvs[rr][0] = mu; mvs[rr][1] = rsqrtf(s2*(1.0f/128.0f) + 1e-5f); }
    }
    __syncthreads();
    float g = lng[col], bb = lnb[col];
    #pragma unroll
    for (int r=0;r<8;r++){
        int rr = rg*8 + r;
        if (base + rr < nc){
            float o = (acc[r] - mvs[rr][0]) * mvs[rr][1] * g + bb;
            h0c[(size_t)(base+rr)*PP + col] = o;
        }
    }
}

// ---------------- K4: [rows x 128] @ [128 x 512] + bih + bhh ----------------
__global__ __launch_bounds__(512) void k_pre(const float* __restrict__ inM,
        const float* __restrict__ wih, const float* __restrict__ bih, const float* __restrict__ bhh,
        const int* __restrict__ cntPtr, int fixedCount, float* __restrict__ outPre){
    int nc = cntPtr ? cntPtr[0] : fixedCount;
    int base = blockIdx.x*32;
    if (base >= nc) return;
    __shared__ float hs[32][PP];
    int tid = threadIdx.x;
    for (int i = tid; i < 32*PP; i += 512){
        int rr = i >> 7;
        if (base + rr < nc) hs[rr][i & 127] = inM[(size_t)(base+rr)*PP + (i & 127)];
    }
    __syncthreads();
    float bias = bih[tid] + bhh[tid];
    float acc[32];
    #pragma unroll
    for (int r=0;r<32;r++) acc[r] = bias;
    const float* wc = wih + tid;
    for (int k=0;k<PP;k+=4){
        float w0 = wc[(k+0)*GG], w1 = wc[(k+1)*GG], w2 = wc[(k+2)*GG], w3 = wc[(k+3)*GG];
        #pragma unroll
        for (int r=0;r<32;r++){
            float4 hv = *reinterpret_cast<const float4*>(&hs[r][k]);
            acc[r] = fmaf(hv.x, w0, acc[r]);
            acc[r] = fmaf(hv.y, w1, acc[r]);
            acc[r] = fmaf(hv.z, w2, acc[r]);
            acc[r] = fmaf(hv.w, w3, acc[r]);
        }
    }
    #pragma unroll
    for (int r=0;r<32;r++)
        if (base + r < nc) outPre[(size_t)(base+r)*GG + tid] = acc[r];
}

// ---------------- K5: LSTM recurrence, TWO batch rows per block ----------------
// 256 blocks x 512 threads = exactly 1 block/CU on 256 CUs, no launch_bounds
// min-waves pressure (VGPR cap 256 -> w[128] stays in registers, no spill).
// Thread j holds Whh column j; the column is reused for both batch rows.
__global__ __launch_bounds__(512) void k_lstm2(
    const float* __restrict__ whh, const float* __restrict__ pre,
    const float* __restrict__ pretab, const int* __restrict__ posIdx,
    const int* __restrict__ recIdx, float* __restrict__ hState, float* __restrict__ cState,
    float* __restrict__ hsOut, int t0, int Tc, int layer)
{
    const int b0 = blockIdx.x*2, b1 = b0 + 1;
    const int j = threadIdx.x;
    float w[128];
    #pragma unroll
    for (int k=0;k<128;k++) w[k] = whh[k*GG + j];   // column j of Whh in VGPRs
    __shared__ float h0s[HH], h1s[HH];
    __shared__ float g0s[GG], g1s[GG];
    __shared__ float hp0[HH], hp1[HH];
    float c_ = 0.f;
    if (j < HH){ h0s[j] = hState[b0*HH + j]; c_ = cState[b0*HH + j]; }
    else if (j < 2*HH){ h1s[j-HH] = hState[b1*HH + (j-HH)]; c_ = cState[b1*HH + (j-HH)]; }
    __syncthreads();
    for (int t = t0; t < t0 + Tc; t++){
        // early-issue previous step's hs stores (overlap with this step's FMAs)
        if (hsOut && t > t0){
            if (j >= 256 && j < 384)      hsOut[((size_t)(t-1-t0)*BB + b0)*HH + (j-256)] = hp0[j-256];
            else if (j >= 384)            hsOut[((size_t)(t-1-t0)*BB + b1)*HH + (j-384)] = hp1[j-384];
        }
        float p0, p1;
        if (layer == 0){
            int q0 = posIdx[(size_t)b0*TT + t];
            int q1 = posIdx[(size_t)b1*TT + t];
            const float* s0 = (q0 >= 0) ? (pre + (size_t)q0*GG)
                                        : (pretab + (size_t)recIdx[(size_t)b0*TT + t]*GG);
            const float* s1 = (q1 >= 0) ? (pre + (size_t)q1*GG)
                                        : (pretab + (size_t)recIdx[(size_t)b1*TT + t]*GG);
            p0 = s0[j]; p1 = s1[j];
        } else {
            p0 = pre[((size_t)(t-t0)*BB + b0)*GG + j];
            p1 = pre[((size_t)(t-t0)*BB + b1)*GG + j];
        }
        float a00=0.f, a01=0.f, a10=0.f, a11=0.f;
        #pragma unroll
        for (int k=0;k<128;k+=4){
            float4 x0 = *reinterpret_cast<const float4*>(&h0s[k]);
            float4 y0 = *reinterpret_cast<const float4*>(&h1s[k]);
            a00 = fmaf(x0.x, w[k+0], a00); a01 = fmaf(x0.y, w[k+1], a01);
            a00 = fmaf(x0.z, w[k+2], a00); a01 = fmaf(x0.w, w[k+3], a01);
            a10 = fmaf(y0.x, w[k+0], a10); a11 = fmaf(y0.y, w[k+1], a11);
            a10 = fmaf(y0.z, w[k+2], a10); a11 = fmaf(y0.w, w[k+3], a11);
        }
        g0s[j] = p0 + (a00 + a01);
        g1s[j] = p1 + (a10 + a11);
        __syncthreads();
        if (j < HH){
            float gi = g0s[j], gf = g0s[HH+j], gg = g0s[2*HH+j], go = g0s[3*HH+j];
            c_ = sig_f(gf)*c_ + sig_f(gi)*tanhf(gg);
            float hn = sig_f(go)*tanhf(c_);
            h0s[j] = hn; hp0[j] = hn;
        } else if (j < 2*HH){
            int jj = j - HH;
            float gi = g1s[jj], gf = g1s[HH+jj], gg = g1s[2*HH+jj], go = g1s[3*HH+jj];
            c_ = sig_f(gf)*c_ + sig_f(gi)*tanhf(gg);
            float hn = sig_f(go)*tanhf(c_);
            h1s[jj] = hn; hp1[jj] = hn;
        }
        __syncthreads();
    }
    if (hsOut){
        if (j >= 256 && j < 384)      hsOut[((size_t)(Tc-1)*BB + b0)*HH + (j-256)] = hp0[j-256];
        else if (j >= 384)            hsOut[((size_t)(Tc-1)*BB + b1)*HH + (j-384)] = hp1[j-384];
    }
    if (j < HH){ hState[b0*HH + j] = h0s[j]; cState[b0*HH + j] = c_; }
    else if (j < 2*HH){ hState[b1*HH + (j-HH)] = h1s[j-HH]; cState[b1*HH + (j-HH)] = c_; }
}

// ---------------- K6: heads ----------------
__global__ __launch_bounds__(128) void k_head(const float* __restrict__ hS,
        const float* __restrict__ we1, const float* __restrict__ be1,
        const float* __restrict__ we2, const float* __restrict__ be2,
        const float* __restrict__ wr,  const float* __restrict__ br,
        const float* __restrict__ wo,  const float* __restrict__ bo,
        const float* __restrict__ wsv, float* __restrict__ out){
    int b = blockIdx.x, j = threadIdx.x;
    __shared__ float lh[128], e1[128], hr[64];
    lh[j] = hS[b*128 + j];
    __syncthreads();
    float acc = be1[j];
    #pragma unroll
    for (int k=0;k<128;k++) acc += lh[k]*we1[k*128 + j];
    e1[j] = gelu_f(acc);
    if (j < 64){
        float a2 = br[j];
        #pragma unroll
        for (int k=0;k<128;k++) a2 += lh[k]*wr[k*64 + j];
        hr[j] = gelu_f(a2);
    }
    __syncthreads();
    if (j < 64){
        float a3 = be2[j];
        #pragma unroll
        for (int k=0;k<128;k++) a3 += e1[k]*we2[k*64 + j];
        out[BB + b*64 + j] = tanhf(a3);
        float p = hr[j]*wo[j] + lh[j]*wsv[j] + lh[j+64]*wsv[j+64];
        #pragma unroll
        for (int off=32; off; off>>=1) p += __shfl_down(p, off, 64);
        if (j == 0) out[b] = p + bo[0];
    }
}

extern "C" void kernel_launch(void* const* d_in, const int* in_sizes, int n_in,
                              void* d_out, int out_size, void* d_ws, size_t ws_size,
                              hipStream_t stream) {
    const float* x     = (const float*)d_in[0];
    const float* wproj = (const float*)d_in[1];
    const float* bproj = (const float*)d_in[2];
    const float* lng   = (const float*)d_in[3];
    const float* lnb   = (const float*)d_in[4];
    const float* wih0  = (const float*)d_in[5];
    const float* whh0  = (const float*)d_in[6];
    const float* bih0  = (const float*)d_in[7];
    const float* bhh0  = (const float*)d_in[8];
    const float* wih1  = (const float*)d_in[9];
    const float* whh1  = (const float*)d_in[10];
    const float* bih1  = (const float*)d_in[11];
    const float* bhh1  = (const float*)d_in[12];
    const float* we1   = (const float*)d_in[13];
    const float* be1   = (const float*)d_in[14];
    const float* we2   = (const float*)d_in[15];
    const float* be2   = (const float*)d_in[16];
    const float* wr    = (const float*)d_in[17];
    const float* br    = (const float*)d_in[18];
    const float* wo    = (const float*)d_in[19];
    const float* bo    = (const float*)d_in[20];
    const float* wsv   = (const float*)d_in[21];
    float* out = (float*)d_out;

    const size_t BT = (size_t)BB*TT;
    static const int cands[12] = {90,60,45,30,20,15,10,6,5,3,2,1};
    size_t offs[12];
    auto plan = [&](int tc, size_t* o)->size_t{
        size_t NCc = (size_t)(TT / tc);
        size_t cur = 0;
        auto take = [&](size_t bytes){ size_t r = cur; cur = (cur + bytes + 255) & ~(size_t)255; return r; };
        o[0]  = take(BT*4);                 // has
        o[1]  = take(BT*4);                 // recIdx
        o[2]  = take(BT*4);                 // posIdx
        o[3]  = take(BT*4);                 // list
        o[4]  = take((size_t)BB*NCc*4);     // cnt_bc
        o[5]  = take((size_t)BB*NCc*4);     // base_bc
        o[6]  = take(NCc*4);                // cntTotal
        o[7]  = take((size_t)TAB*PP*4);     // tab1
        o[8]  = take((size_t)TAB*GG*4);     // tab2
        o[9]  = take((size_t)4*BB*HH*4);    // states h0,c0,h1,c1
        o[10] = take((size_t)BB*tc*PP*4);   // h0buf / hs0buf (aliased)
        o[11] = take((size_t)BB*tc*GG*4);   // prebuf (pre0 then pre1, aliased)
        return cur;
    };
    int Tc = 1;
    for (int ci=0; ci<12; ci++){
        if (plan(cands[ci], offs) <= ws_size){ Tc = cands[ci]; break; }
    }
    plan(Tc, offs);
    char* wsb = (char*)d_ws;
    float* f_has    = (float*)(wsb + offs[0]);
    int*   i_rec    = (int*)  (wsb + offs[1]);
    int*   i_pos    = (int*)  (wsb + offs[2]);
    int*   i_list   = (int*)  (wsb + offs[3]);
    int*   i_cntbc  = (int*)  (wsb + offs[4]);
    int*   i_basebc = (int*)  (wsb + offs[5]);
    int*   i_cnt    = (int*)  (wsb + offs[6]);
    float* f_tab1   = (float*)(wsb + offs[7]);
    float* f_tab2   = (float*)(wsb + offs[8]);
    float* f_st     = (float*)(wsb + offs[9]);
    float* f_h0     = (float*)(wsb + offs[10]);
    float* f_pre    = (float*)(wsb + offs[11]);
    const int NC = TT / Tc;

    float* st_h0 = f_st;
    float* st_c0 = f_st + (size_t)BB*HH;
    float* st_h1 = f_st + (size_t)2*BB*HH;
    float* st_c1 = f_st + (size_t)3*BB*HH;

    { int n = 4*BB*HH; k_zero<<<(n+255)/256, 256, 0, stream>>>(f_st, n); }
    k_has <<<(int)(BT/4), 256, 0, stream>>>(x, f_has);
    k_rec <<<(BB+63)/64, 64, 0, stream>>>(f_has, i_rec, i_cntbc, Tc, NC);
    k_scan<<<NC, 512, 0, stream>>>(i_cntbc, i_basebc, i_cnt, NC);
    k_pos <<<(BB+63)/64, 64, 0, stream>>>(f_has, i_basebc, i_pos, i_list, Tc, NC);
    k_tab1<<<TAB, 128, 0, stream>>>(wproj, bproj, lng, lnb, f_tab1);
    k_tab2<<<TAB, 512, 0, stream>>>(f_tab1, wih0, bih0, bhh0, f_tab2);

    const int rowsPerChunk = BB*Tc;
    for (int c=0; c<NC; c++){
        const int* listc = i_list + (size_t)c*rowsPerChunk;
        k_proj<<<(rowsPerChunk+15)/16, 256, 0, stream>>>(x, wproj, bproj, lng, lnb,
                listc, i_cnt + c, f_h0);
        k_pre <<<(rowsPerChunk+31)/32, 512, 0, stream>>>(f_h0, wih0, bih0, bhh0,
                i_cnt + c, 0, f_pre);
        k_lstm2<<<BB/2, 512, 0, stream>>>(whh0, f_pre, f_tab2, i_pos, i_rec,
                st_h0, st_c0, f_h0, c*Tc, Tc, 0);
        k_pre <<<(rowsPerChunk+31)/32, 512, 0, stream>>>(f_h0, wih1, bih1, bhh1,
                nullptr, rowsPerChunk, f_pre);
        k_lstm2<<<BB/2, 512, 0, stream>>>(whh1, f_pre, nullptr, nullptr, nullptr,
                st_h1, st_c1, nullptr, c*Tc, Tc, 1);
    }
    k_head<<<BB, 128, 0, stream>>>(st_h1, we1, be1, we2, be2, wr, br, wo, bo, wsv, out);
}

// Round 3
// 7046.669 us; speedup vs baseline: 1.1251x; 1.1195x over previous
//
#include <hip/hip_runtime.h>
#include <math.h>

#define BB 512
#define TT 720
#define DD 774
#define PP 128
#define HH 128
#define GG 512      // 4*H
#define DP2 776     // D+2
#define TAB 721

__device__ __forceinline__ float gelu_f(float v){
    return 0.5f*v*(1.0f + erff(v*0.70710678118654752f));
}
__device__ __forceinline__ float sig_f(float v){
    return 1.0f/(1.0f + __expf(-v));
}
__device__ __forceinline__ float rdlane(float v, int lane){
    return __int_as_float(__builtin_amdgcn_readlane(__float_as_int(v), lane));
}

// ---------------- K0: zero states ----------------
__global__ void k_zero(float* __restrict__ p, int n){
    int i = blockIdx.x*256 + threadIdx.x;
    if (i < n) p[i] = 0.f;
}

// ---------------- K1: has flags (wave per row) ----------------
__global__ __launch_bounds__(256) void k_has(const float* __restrict__ x, float* __restrict__ has){
    int wid  = blockIdx.x*4 + (threadIdx.x >> 6);
    int lane = threadIdx.x & 63;
    const float2* row = reinterpret_cast<const float2*>(x + (size_t)wid*DD); // 774 floats = 387 float2
    float s = 0.f;
    #pragma unroll
    for (int i=0;i<6;i++){ float2 v = row[lane + i*64]; s += fabsf(v.x)+fabsf(v.y); }
    if (lane < 3){ float2 v = row[384 + lane]; s += fabsf(v.x)+fabsf(v.y); }
    #pragma unroll
    for (int off=32; off; off>>=1) s += __shfl_down(s, off, 64);
    if (lane == 0) has[wid] = (s > 1e-6f) ? 1.0f : 0.0f;
}

// ---------------- K2: recency + per-(b,chunk) dense counts ----------------
__global__ void k_rec(const float* __restrict__ has, int* __restrict__ recIdx,
                      int* __restrict__ cnt_bc, int Tc, int NC){
    int b = blockIdx.x*64 + threadIdx.x;
    if (b >= BB) return;
    const float* hp = has + (size_t)b*TT;
    int* rp = recIdx + (size_t)b*TT;
    int last = -1, cl = 0, c = 0;
    for (int t=0;t<TT;t++){
        if (t == (c+1)*Tc){ cnt_bc[b*NC + c] = cl; cl = 0; c++; }
        if (hp[t] > 0.5f){ last = t; cl++; }
        rp[t] = t - last;   // dense -> 0 ; sparse -> k in [1,720]
    }
    cnt_bc[b*NC + c] = cl;
}

// ---------------- K2b: exclusive prefix over b per chunk ----------------
__global__ __launch_bounds__(512) void k_scan(const int* __restrict__ cnt_bc, int* __restrict__ base_bc,
                                              int* __restrict__ cntTotal, int NC){
    int c = blockIdx.x;
    int b = threadIdx.x;
    int v = cnt_bc[b*NC + c];
    int lane = b & 63, w = b >> 6;
    int xv = v;
    #pragma unroll
    for (int off=1; off<64; off<<=1){
        int y = __shfl_up(xv, off, 64);
        if (lane >= off) xv += y;
    }
    __shared__ int wsums[8];
    if (lane == 63) wsums[w] = xv;
    __syncthreads();
    if (b == 0){
        int run = 0;
        #pragma unroll
        for (int i=0;i<8;i++){ int tv = wsums[i]; wsums[i] = run; run += tv; }
        cntTotal[c] = run;
    }
    __syncthreads();
    base_bc[b*NC + c] = wsums[w] + xv - v;  // exclusive prefix
}

// ---------------- K2c: dense-row lists + positions ----------------
__global__ void k_pos(const float* __restrict__ has, const int* __restrict__ base_bc,
                      int* __restrict__ posIdx, int* __restrict__ list, int Tc, int NC){
    int b = blockIdx.x*64 + threadIdx.x;
    if (b >= BB) return;
    const float* hp = has + (size_t)b*TT;
    int c = 0;
    int pos = base_bc[b*NC + 0];
    for (int t=0;t<TT;t++){
        if (t == (c+1)*Tc){ c++; pos = base_bc[b*NC + c]; }
        int r = b*TT + t;
        if (hp[t] > 0.5f){
            posIdx[r] = pos;
            list[(size_t)c*((size_t)BB*Tc) + pos] = r;
            pos++;
        } else {
            posIdx[r] = -1;
        }
    }
}

// ---------------- K_tab1: h0 rows for sparse rows, per rec index ----------------
__global__ __launch_bounds__(128) void k_tab1(const float* __restrict__ wp, const float* __restrict__ bp,
        const float* __restrict__ lng, const float* __restrict__ lnb, float* __restrict__ tab1){
    int k = blockIdx.x, j = threadIdx.x;
    float rec = (float)k * (1.0f/720.0f);
    float v = gelu_f(rec * wp[775*PP + j] + bp[j]);
    int lane = j & 63, w = j >> 6;
    __shared__ float red[2];
    float s = v;
    #pragma unroll
    for (int off=32; off; off>>=1) s += __shfl_xor(s, off, 64);
    if (lane == 0) red[w] = s;
    __syncthreads();
    float mu = (red[0] + red[1]) * (1.0f/128.0f);
    __syncthreads();
    float d = v - mu, s2 = d*d;
    #pragma unroll
    for (int off=32; off; off>>=1) s2 += __shfl_xor(s2, off, 64);
    if (lane == 0) red[w] = s2;
    __syncthreads();
    float var = (red[0] + red[1]) * (1.0f/128.0f);
    tab1[k*PP + j] = d * rsqrtf(var + 1e-5f) * lng[j] + lnb[j];
}

// ---------------- K_tab2: pre0 rows for sparse rows ----------------
__global__ __launch_bounds__(512) void k_tab2(const float* __restrict__ tab1, const float* __restrict__ wih,
        const float* __restrict__ bih, const float* __restrict__ bhh, float* __restrict__ tab2){
    int k = blockIdx.x, j = threadIdx.x;
    __shared__ float hrow[PP];
    if (j < PP) hrow[j] = tab1[k*PP + j];
    __syncthreads();
    float acc = bih[j] + bhh[j];
    #pragma unroll
    for (int kk=0; kk<PP; kk++) acc += hrow[kk]*wih[kk*GG + j];
    tab2[(size_t)k*GG + j] = acc;
}

// ---------------- K3: projection + GELU + LN for dense rows of one chunk ----------------
__global__ __launch_bounds__(256) void k_proj(const float* __restrict__ x,
        const float* __restrict__ wp, const float* __restrict__ bp,
        const float* __restrict__ lng, const float* __restrict__ lnb,
        const int* __restrict__ listc, const int* __restrict__ cntPtr,
        float* __restrict__ h0c){
    int nc = cntPtr[0];
    int base = blockIdx.x*16;
    if (base >= nc) return;
    int nrows = min(16, nc - base);
    __shared__ float xs[16][DP2];
    __shared__ float hls[16][PP];
    __shared__ float mvs[16][2];
    const int tid = threadIdx.x;
    for (int rr=0; rr<16; rr++){
        if (rr < nrows){
            int row = listc[base + rr];
            const float* xr = x + (size_t)row*DD;
            for (int d = tid; d < DD; d += 256) xs[rr][d] = xr[d];
            if (tid == 0){ xs[rr][774] = 1.0f; xs[rr][775] = 0.0f; } // has=1, rec=0 for dense rows
        }
    }
    __syncthreads();
    int col = tid & 127, rg = tid >> 7;
    float acc[8];
    #pragma unroll
    for (int r=0;r<8;r++) acc[r] = bp[col];
    const float* wcol = wp + col;
    for (int d=0; d<DP2; d+=4){
        float w0 = wcol[(d+0)*PP], w1 = wcol[(d+1)*PP], w2 = wcol[(d+2)*PP], w3 = wcol[(d+3)*PP];
        #pragma unroll
        for (int r=0;r<8;r++){
            float4 xv = *reinterpret_cast<const float4*>(&xs[rg*8 + r][d]);
            acc[r] = fmaf(xv.x, w0, acc[r]);
            acc[r] = fmaf(xv.y, w1, acc[r]);
            acc[r] = fmaf(xv.z, w2, acc[r]);
            acc[r] = fmaf(xv.w, w3, acc[r]);
        }
    }
    #pragma unroll
    for (int r=0;r<8;r++){ acc[r] = gelu_f(acc[r]); hls[rg*8 + r][col] = acc[r]; }
    __syncthreads();
    int w = tid >> 6, lane = tid & 63;
    for (int rr = w*4; rr < w*4 + 4; rr++){
        float s = hls[rr][lane] + hls[rr][lane + 64];
        #pragma unroll
        for (int off=32; off; off>>=1) s += __shfl_xor(s, off, 64);
        float mu = s * (1.0f/128.0f);
        float d0 = hls[rr][lane]-mu, d1 = hls[rr][lane+64]-mu;
        float s2 = d0*d0 + d1*d1;
        #pragma unroll
        for (int off=32; off; off>>=1) s2 += __shfl_xor(s2, off, 64);
        if (lane == 0){ mvs[rr][0] = mu; mvs[rr][1] = rsqrtf(s2*(1.0f/128.0f) + 1e-5f); }
    }
    __syncthreads();
    float g = lng[col], bb = lnb[col];
    #pragma unroll
    for (int r=0;r<8;r++){
        int rr = rg*8 + r;
        if (base + rr < nc){
            float o = (acc[r] - mvs[rr][0]) * mvs[rr][1] * g + bb;
            h0c[(size_t)(base+rr)*PP + col] = o;
        }
    }
}

// ---------------- K4: [rows x 128] @ [128 x 512] + bih + bhh ----------------
__global__ __launch_bounds__(512) void k_pre(const float* __restrict__ inM,
        const float* __restrict__ wih, const float* __restrict__ bih, const float* __restrict__ bhh,
        const int* __restrict__ cntPtr, int fixedCount, float* __restrict__ outPre){
    int nc = cntPtr ? cntPtr[0] : fixedCount;
    int base = blockIdx.x*32;
    if (base >= nc) return;
    __shared__ float hs[32][PP];
    int tid = threadIdx.x;
    for (int i = tid; i < 32*PP; i += 512){
        int rr = i >> 7;
        if (base + rr < nc) hs[rr][i & 127] = inM[(size_t)(base+rr)*PP + (i & 127)];
    }
    __syncthreads();
    float bias = bih[tid] + bhh[tid];
    float acc[32];
    #pragma unroll
    for (int r=0;r<32;r++) acc[r] = bias;
    const float* wc = wih + tid;
    for (int k=0;k<PP;k+=4){
        float w0 = wc[(k+0)*GG], w1 = wc[(k+1)*GG], w2 = wc[(k+2)*GG], w3 = wc[(k+3)*GG];
        #pragma unroll
        for (int r=0;r<32;r++){
            float4 hv = *reinterpret_cast<const float4*>(&hs[r][k]);
            acc[r] = fmaf(hv.x, w0, acc[r]);
            acc[r] = fmaf(hv.y, w1, acc[r]);
            acc[r] = fmaf(hv.z, w2, acc[r]);
            acc[r] = fmaf(hv.w, w3, acc[r]);
        }
    }
    #pragma unroll
    for (int r=0;r<32;r++)
        if (base + r < nc) outPre[(size_t)(base+r)*GG + tid] = acc[r];
}

// ---------------- K5: LSTM recurrence, TWO batch rows per block ----------------
// LDS-pipe fix: ONE fully-divergent ds_read_b128 per wave per step fetches the
// entire 2x128 h state (lane l holds hcat[4l..4l+3]); h[k] is then broadcast
// via v_readlane (VALU, per-SIMD pipe) into the FMA's SGPR operand. This cuts
// per-CU LDS instructions per step from 512 to ~16.
__global__ __launch_bounds__(512) void k_lstm3(
    const float* __restrict__ whh, const float* __restrict__ pre,
    const float* __restrict__ pretab, const int* __restrict__ posIdx,
    const int* __restrict__ recIdx, float* __restrict__ hState, float* __restrict__ cState,
    float* __restrict__ hsOut, int t0, int Tc, int layer)
{
    const int b0 = blockIdx.x*2, b1 = b0 + 1;
    const int j = threadIdx.x;
    const int lane = j & 63;
    float w[128];
    #pragma unroll
    for (int k=0;k<128;k++) w[k] = whh[k*GG + j];   // column j of Whh in VGPRs
    __shared__ float hcat[2*HH];     // h0[0..127] then h1[0..127]
    __shared__ float g0s[GG], g1s[GG];
    __shared__ float hp0[HH], hp1[HH];
    float c_ = 0.f;
    if (j < HH){ hcat[j] = hState[b0*HH + j]; c_ = cState[b0*HH + j]; }
    else if (j < 2*HH){ hcat[j] = hState[b1*HH + (j-HH)]; c_ = cState[b1*HH + (j-HH)]; }
    __syncthreads();
    for (int t = t0; t < t0 + Tc; t++){
        // early-issue previous step's hs stores (overlap with this step's FMAs)
        if (hsOut && t > t0){
            if (j >= 256 && j < 384)      hsOut[((size_t)(t-1-t0)*BB + b0)*HH + (j-256)] = hp0[j-256];
            else if (j >= 384)            hsOut[((size_t)(t-1-t0)*BB + b1)*HH + (j-384)] = hp1[j-384];
        }
        float p0, p1;
        if (layer == 0){
            int q0 = posIdx[(size_t)b0*TT + t];
            int q1 = posIdx[(size_t)b1*TT + t];
            const float* s0 = (q0 >= 0) ? (pre + (size_t)q0*GG)
                                        : (pretab + (size_t)recIdx[(size_t)b0*TT + t]*GG);
            const float* s1 = (q1 >= 0) ? (pre + (size_t)q1*GG)
                                        : (pretab + (size_t)recIdx[(size_t)b1*TT + t]*GG);
            p0 = s0[j]; p1 = s1[j];
        } else {
            p0 = pre[((size_t)(t-t0)*BB + b0)*GG + j];
            p1 = pre[((size_t)(t-t0)*BB + b1)*GG + j];
        }
        // one divergent 16B read per lane: lane l holds hcat[4l .. 4l+3]
        float4 hv4 = *reinterpret_cast<const float4*>(&hcat[4*lane]);
        float hva[4] = {hv4.x, hv4.y, hv4.z, hv4.w};
        float a00=0.f, a01=0.f, a10=0.f, a11=0.f;
        #pragma unroll
        for (int k=0;k<128;k+=2){
            // h0[k] lives in lane (k>>2) comp (k&3); h1[k] in lane 32+(k>>2)
            float h00 = rdlane(hva[k & 3],        (k >> 2));
            float h10 = rdlane(hva[k & 3],        32 + (k >> 2));
            float h01 = rdlane(hva[(k+1) & 3],    ((k+1) >> 2));
            float h11 = rdlane(hva[(k+1) & 3],    32 + ((k+1) >> 2));
            a00 = fmaf(h00, w[k],   a00);
            a10 = fmaf(h10, w[k],   a10);
            a01 = fmaf(h01, w[k+1], a01);
            a11 = fmaf(h11, w[k+1], a11);
        }
        g0s[j] = p0 + (a00 + a01);
        g1s[j] = p1 + (a10 + a11);
        __syncthreads();
        if (j < HH){
            float gi = g0s[j], gf = g0s[HH+j], gg = g0s[2*HH+j], go = g0s[3*HH+j];
            c_ = sig_f(gf)*c_ + sig_f(gi)*tanhf(gg);
            float hn = sig_f(go)*tanhf(c_);
            hcat[j] = hn; hp0[j] = hn;
        } else if (j < 2*HH){
            int jj = j - HH;
            float gi = g1s[jj], gf = g1s[HH+jj], gg = g1s[2*HH+jj], go = g1s[3*HH+jj];
            c_ = sig_f(gf)*c_ + sig_f(gi)*tanhf(gg);
            float hn = sig_f(go)*tanhf(c_);
            hcat[j] = hn; hp1[jj] = hn;
        }
        __syncthreads();
    }
    if (hsOut){
        if (j >= 256 && j < 384)      hsOut[((size_t)(Tc-1)*BB + b0)*HH + (j-256)] = hp0[j-256];
        else if (j >= 384)            hsOut[((size_t)(Tc-1)*BB + b1)*HH + (j-384)] = hp1[j-384];
    }
    if (j < HH){ hState[b0*HH + j] = hcat[j]; cState[b0*HH + j] = c_; }
    else if (j < 2*HH){ hState[b1*HH + (j-HH)] = hcat[j]; cState[b1*HH + (j-HH)] = c_; }
}

// ---------------- K6: heads ----------------
__global__ __launch_bounds__(128) void k_head(const float* __restrict__ hS,
        const float* __restrict__ we1, const float* __restrict__ be1,
        const float* __restrict__ we2, const float* __restrict__ be2,
        const float* __restrict__ wr,  const float* __restrict__ br,
        const float* __restrict__ wo,  const float* __restrict__ bo,
        const float* __restrict__ wsv, float* __restrict__ out){
    int b = blockIdx.x, j = threadIdx.x;
    __shared__ float lh[128], e1[128], hr[64];
    lh[j] = hS[b*128 + j];
    __syncthreads();
    float acc = be1[j];
    #pragma unroll
    for (int k=0;k<128;k++) acc += lh[k]*we1[k*128 + j];
    e1[j] = gelu_f(acc);
    if (j < 64){
        float a2 = br[j];
        #pragma unroll
        for (int k=0;k<128;k++) a2 += lh[k]*wr[k*64 + j];
        hr[j] = gelu_f(a2);
    }
    __syncthreads();
    if (j < 64){
        float a3 = be2[j];
        #pragma unroll
        for (int k=0;k<128;k++) a3 += e1[k]*we2[k*64 + j];
        out[BB + b*64 + j] = tanhf(a3);
        float p = hr[j]*wo[j] + lh[j]*wsv[j] + lh[j+64]*wsv[j+64];
        #pragma unroll
        for (int off=32; off; off>>=1) p += __shfl_down(p, off, 64);
        if (j == 0) out[b] = p + bo[0];
    }
}

extern "C" void kernel_launch(void* const* d_in, const int* in_sizes, int n_in,
                              void* d_out, int out_size, void* d_ws, size_t ws_size,
                              hipStream_t stream) {
    const float* x     = (const float*)d_in[0];
    const float* wproj = (const float*)d_in[1];
    const float* bproj = (const float*)d_in[2];
    const float* lng   = (const float*)d_in[3];
    const float* lnb   = (const float*)d_in[4];
    const float* wih0  = (const float*)d_in[5];
    const float* whh0  = (const float*)d_in[6];
    const float* bih0  = (const float*)d_in[7];
    const float* bhh0  = (const float*)d_in[8];
    const float* wih1  = (const float*)d_in[9];
    const float* whh1  = (const float*)d_in[10];
    const float* bih1  = (const float*)d_in[11];
    const float* bhh1  = (const float*)d_in[12];
    const float* we1   = (const float*)d_in[13];
    const float* be1   = (const float*)d_in[14];
    const float* we2   = (const float*)d_in[15];
    const float* be2   = (const float*)d_in[16];
    const float* wr    = (const float*)d_in[17];
    const float* br    = (const float*)d_in[18];
    const float* wo    = (const float*)d_in[19];
    const float* bo    = (const float*)d_in[20];
    const float* wsv   = (const float*)d_in[21];
    float* out = (float*)d_out;

    const size_t BT = (size_t)BB*TT;
    static const int cands[12] = {90,60,45,30,20,15,10,6,5,3,2,1};
    size_t offs[12];
    auto plan = [&](int tc, size_t* o)->size_t{
        size_t NCc = (size_t)(TT / tc);
        size_t cur = 0;
        auto take = [&](size_t bytes){ size_t r = cur; cur = (cur + bytes + 255) & ~(size_t)255; return r; };
        o[0]  = take(BT*4);                 // has
        o[1]  = take(BT*4);                 // recIdx
        o[2]  = take(BT*4);                 // posIdx
        o[3]  = take(BT*4);                 // list
        o[4]  = take((size_t)BB*NCc*4);     // cnt_bc
        o[5]  = take((size_t)BB*NCc*4);     // base_bc
        o[6]  = take(NCc*4);                // cntTotal
        o[7]  = take((size_t)TAB*PP*4);     // tab1
        o[8]  = take((size_t)TAB*GG*4);     // tab2
        o[9]  = take((size_t)4*BB*HH*4);    // states h0,c0,h1,c1
        o[10] = take((size_t)BB*tc*PP*4);   // h0buf / hs0buf (aliased)
        o[11] = take((size_t)BB*tc*GG*4);   // prebuf (pre0 then pre1, aliased)
        return cur;
    };
    int Tc = 1;
    for (int ci=0; ci<12; ci++){
        if (plan(cands[ci], offs) <= ws_size){ Tc = cands[ci]; break; }
    }
    plan(Tc, offs);
    char* wsb = (char*)d_ws;
    float* f_has    = (float*)(wsb + offs[0]);
    int*   i_rec    = (int*)  (wsb + offs[1]);
    int*   i_pos    = (int*)  (wsb + offs[2]);
    int*   i_list   = (int*)  (wsb + offs[3]);
    int*   i_cntbc  = (int*)  (wsb + offs[4]);
    int*   i_basebc = (int*)  (wsb + offs[5]);
    int*   i_cnt    = (int*)  (wsb + offs[6]);
    float* f_tab1   = (float*)(wsb + offs[7]);
    float* f_tab2   = (float*)(wsb + offs[8]);
    float* f_st     = (float*)(wsb + offs[9]);
    float* f_h0     = (float*)(wsb + offs[10]);
    float* f_pre    = (float*)(wsb + offs[11]);
    const int NC = TT / Tc;

    float* st_h0 = f_st;
    float* st_c0 = f_st + (size_t)BB*HH;
    float* st_h1 = f_st + (size_t)2*BB*HH;
    float* st_c1 = f_st + (size_t)3*BB*HH;

    { int n = 4*BB*HH; k_zero<<<(n+255)/256, 256, 0, stream>>>(f_st, n); }
    k_has <<<(int)(BT/4), 256, 0, stream>>>(x, f_has);
    k_rec <<<(BB+63)/64, 64, 0, stream>>>(f_has, i_rec, i_cntbc, Tc, NC);
    k_scan<<<NC, 512, 0, stream>>>(i_cntbc, i_basebc, i_cnt, NC);
    k_pos <<<(BB+63)/64, 64, 0, stream>>>(f_has, i_basebc, i_pos, i_list, Tc, NC);
    k_tab1<<<TAB, 128, 0, stream>>>(wproj, bproj, lng, lnb, f_tab1);
    k_tab2<<<TAB, 512, 0, stream>>>(f_tab1, wih0, bih0, bhh0, f_tab2);

    const int rowsPerChunk = BB*Tc;
    for (int c=0; c<NC; c++){
        const int* listc = i_list + (size_t)c*rowsPerChunk;
        k_proj<<<(rowsPerChunk+15)/16, 256, 0, stream>>>(x, wproj, bproj, lng, lnb,
                listc, i_cnt + c, f_h0);
        k_pre <<<(rowsPerChunk+31)/32, 512, 0, stream>>>(f_h0, wih0, bih0, bhh0,
                i_cnt + c, 0, f_pre);
        k_lstm3<<<BB/2, 512, 0, stream>>>(whh0, f_pre, f_tab2, i_pos, i_rec,
                st_h0, st_c0, f_h0, c*Tc, Tc, 0);
        k_pre <<<(rowsPerChunk+31)/32, 512, 0, stream>>>(f_h0, wih1, bih1, bhh1,
                nullptr, rowsPerChunk, f_pre);
        k_lstm3<<<BB/2, 512, 0, stream>>>(whh1, f_pre, nullptr, nullptr, nullptr,
                st_h1, st_c1, nullptr, c*Tc, Tc, 1);
    }
    k_head<<<BB, 128, 0, stream>>>(st_h1, we1, be1, we2, be2, wr, br, wo, bo, wsv, out);
}